// Round 1
// baseline (3102.438 us; speedup 1.0000x reference)
//
#include <hip/hip_runtime.h>
#include <cstdint>
#include <cstddef>

// DSDHLoss: faithful DCC loop on bitmask representation.
// B (+-1) -> 64-bit column masks + row-major bit-planes; Ybuf (0/1) -> masks.
// S=B B^T and R=B Y^T via popcount (exact integers == fp32 reference values).
// WS requirement ~5.1 MB.

#define NT 100000
#define WPR 1568      // padded u64 words per bit-row
#define NWREAL 1563   // ceil(100000/64)
#define NGRP 1563
#define ETA_MU 55.0f
#define LAM 0.1f

typedef unsigned long long u64;

__device__ inline u64 transpose64(u64 x, int lane) {
  const u64 ms[6] = {0x5555555555555555ull,0x3333333333333333ull,0x0F0F0F0F0F0F0F0Full,
                     0x00FF00FF00FF00FFull,0x0000FFFF0000FFFFull,0x00000000FFFFFFFFull};
#pragma unroll
  for (int si = 0; si < 6; ++si) {
    int s = 1 << si;
    u64 m = ms[si];
    u64 y = __shfl_xor(x, s, 64);
    if ((lane & s) == 0) x = (x & m) | ((y & m) << s);
    else                 x = (x & ~m) | ((y & ~m) >> s);
  }
  return x;
}

__device__ inline int wave_reduce_i32(int v) {
#pragma unroll
  for (int off = 32; off > 0; off >>= 1) v += __shfl_down(v, off, 64);
  return v;
}
__device__ inline double wave_reduce_f64(double v) {
#pragma unroll
  for (int off = 32; off > 0; off >>= 1) v += __shfl_down(v, off, 64);
  return v;
}

__global__ void init_acc(double* acc) {
  if (threadIdx.x < 4) acc[threadIdx.x] = 0.0;
}

// column masks for B and Ybuf; owner[] = -1 everywhere (scatter fills later)
__global__ __launch_bounds__(256) void build_colmasks(
    const float* __restrict__ B, const float* __restrict__ Ybuf,
    u64* __restrict__ Bmask, u64* __restrict__ Ymask, int* __restrict__ owner) {
  int j = blockIdx.x * 256 + threadIdx.x;
  if (j >= NT) return;
  owner[j] = -1;
  u64 bm = 0;
#pragma unroll
  for (int i = 0; i < 64; ++i)
    bm |= ((u64)(B[(size_t)i * NT + j] > 0.0f)) << i;
  u64 m0 = 0, m1 = 0;
#pragma unroll
  for (int c = 0; c < 64; ++c)
    m0 |= ((u64)(Ybuf[(size_t)c * NT + j] > 0.5f)) << c;
#pragma unroll
  for (int c = 64; c < 100; ++c)
    m1 |= ((u64)(Ybuf[(size_t)c * NT + j] > 0.5f)) << (c - 64);
  Bmask[j] = bm;
  Ymask[2 * j] = m0;
  Ymask[2 * j + 1] = m1;
}

// scatter: Ybuf[:, ind[b]] = y[b]; owner[ind[b]] = b; also batch y-masks
__global__ void scatter_y(const float* __restrict__ y, const int* __restrict__ ind,
                          u64* __restrict__ Ymask, u64* __restrict__ ybatch,
                          int* __restrict__ owner) {
  int b = threadIdx.x;
  if (b >= 128) return;
  u64 m0 = 0, m1 = 0;
  for (int c = 0; c < 100; ++c) {
    bool v = y[b * 100 + c] > 0.5f;
    if (c < 64) m0 |= ((u64)v) << c;
    else        m1 |= ((u64)v) << (c - 64);
  }
  ybatch[2 * b] = m0;
  ybatch[2 * b + 1] = m1;
  int col = ind[b];
  Ymask[2 * col] = m0;
  Ymask[2 * col + 1] = m1;
  owner[col] = b;
}

// column masks -> row-major bit planes (wave-level 64x64 bit transpose)
__global__ __launch_bounds__(256) void build_rows(
    const u64* __restrict__ Bmask, const u64* __restrict__ Ymask,
    u64* __restrict__ Brow, u64* __restrict__ Yrow) {
  int g = blockIdx.x * 4 + (threadIdx.x >> 6);
  int lane = threadIdx.x & 63;
  if (g >= NGRP) return;
  int j = g * 64 + lane;
  bool act = j < NT;
  u64 bm = act ? Bmask[j] : 0ull;
  u64 y0 = act ? Ymask[2 * j] : 0ull;
  u64 y1 = act ? Ymask[2 * j + 1] : 0ull;
  u64 tb = transpose64(bm, lane);
  Brow[(size_t)lane * WPR + g] = tb;
  u64 t0 = transpose64(y0, lane);
  Yrow[(size_t)lane * WPR + g] = t0;
  u64 t1 = transpose64(y1, lane);
  if (lane < 36) Yrow[(size_t)(64 + lane) * WPR + g] = t1;
}

__global__ void popcY_k(const u64* __restrict__ Yrow, int* __restrict__ popcY) {
  int c = threadIdx.x;
  if (c >= 100) return;
  int s = 0;
  for (int w = 0; w < NWREAL; ++w) s += __popcll(Yrow[(size_t)c * WPR + w]);
  popcY[c] = s;
}

// K1: partial mismatch counts for S and AND-counts for R, per word-quarter
__global__ __launch_bounds__(256) void k1_sr(
    const u64* __restrict__ Brow, const u64* __restrict__ Yrow,
    int* __restrict__ S_part, int* __restrict__ R_part) {
  int k = blockIdx.x, q = blockIdx.y;
  __shared__ u64 sb[392];
  int w0 = q * 392;
  int nw = NWREAL - w0; if (nw > 392) nw = 392;
  for (int t = threadIdx.x; t < nw; t += 256) sb[t] = Brow[(size_t)k * WPR + w0 + t];
  __syncthreads();
  int wv = threadIdx.x >> 6, lane = threadIdx.x & 63;
  for (int l = wv; l < 64; l += 4) {
    const u64* br = Brow + (size_t)l * WPR + w0;
    int s = 0;
    for (int t = lane; t < nw; t += 64) s += __popcll(sb[t] ^ br[t]);
    s = wave_reduce_i32(s);
    if (lane == 0) S_part[q * 4096 + k * 64 + l] = s;
  }
  for (int c = wv; c < 100; c += 4) {
    const u64* yr = Yrow + (size_t)c * WPR + w0;
    int s = 0;
    for (int t = lane; t < nw; t += 64) s += __popcll(sb[t] & yr[t]);
    s = wave_reduce_i32(s);
    if (lane == 0) R_part[q * 6400 + k * 100 + c] = s;
  }
}

// K2: A = S+lam*I, symmetric GE (no pivot; diag ~1e5 dominant), solve 100 RHS,
// W out in both layouts, G = W W^T.
__global__ __launch_bounds__(256) void k2_solve(
    const int* __restrict__ S_part, const int* __restrict__ R_part,
    const int* __restrict__ popcY, float* __restrict__ Wr,
    float* __restrict__ Wc, float* __restrict__ G) {
  __shared__ float A[64 * 68];
  __shared__ float X[64 * 105];
  __shared__ float Dinv[64];
  int tid = threadIdx.x;
  int wv = tid >> 6, lane = tid & 63;
  for (int e = tid; e < 4096; e += 256) {
    int mm = S_part[e] + S_part[4096 + e] + S_part[8192 + e] + S_part[12288 + e];
    int k = e >> 6, l = e & 63;
    float v = (float)(NT - 2 * mm);
    if (k == l) v += LAM;
    A[k * 68 + l] = v;
  }
  for (int e = tid; e < 6400; e += 256) {
    int rr = R_part[e] + R_part[6400 + e] + R_part[12800 + e] + R_part[19200 + e];
    int k = e / 100, c = e - k * 100;
    X[k * 105 + c] = (float)(2 * rr - popcY[c]);
  }
  __syncthreads();
  // elimination: stores unscaled Schur columns below diag, pivots on diag
  for (int j = 0; j < 63; ++j) {
    float rinv = 1.0f / A[j * 68 + j];
    int k = j + 1 + lane;
    if (k < 64) {
      float cr = A[k * 68 + j] * rinv;
      for (int t = j + 1 + wv; t < 64; t += 4)
        A[t * 68 + k] -= A[t * 68 + j] * cr;
    }
    __syncthreads();
  }
  for (int t = tid; t < 64; t += 256) Dinv[t] = 1.0f / A[t * 68 + t];
  __syncthreads();
  if (tid < 100) {
    int c = tid;
    float x[64];
#pragma unroll
    for (int k = 0; k < 64; ++k) x[k] = X[k * 105 + c];
    // forward: t_j = (b_j - sum_{k<j} A[j][k] t_k) / d_j
#pragma unroll
    for (int j = 0; j < 64; ++j) {
      float s = x[j];
#pragma unroll
      for (int k = 0; k < j; ++k) s -= A[j * 68 + k] * x[k];
      x[j] = s * Dinv[j];
    }
    // back: x_j = t_j - (sum_{k>j} A[k][j] x_k) / d_j
#pragma unroll
    for (int j = 62; j >= 0; --j) {
      float s = 0.0f;
#pragma unroll
      for (int k = j + 1; k < 64; ++k) s -= A[k * 68 + j] * x[k];
      x[j] = x[j] + s * Dinv[j];
    }
#pragma unroll
    for (int k = 0; k < 64; ++k) X[k * 105 + c] = x[k];
  }
  __syncthreads();
  for (int e = tid; e < 6400; e += 256) {
    int k = e / 100, c = e - (e / 100) * 100;
    float v = X[k * 105 + c];
    Wr[k * 100 + c] = v;
    Wc[c * 64 + k] = v;
  }
  for (int e = tid; e < 4096; e += 256) {
    int i = e >> 6, l = e & 63;
    float g = 0.0f;
    for (int c = 0; c < 100; ++c) g += X[i * 105 + c] * X[l * 105 + c];
    G[e] = g;
  }
}

// K3: per-column P = W@Ybuf_col + 55*U_col, then exact sequential GS sign sweep.
__global__ __launch_bounds__(256) void k3_gs(
    const float* __restrict__ U, const float* __restrict__ u,
    const int* __restrict__ owner, const float* __restrict__ Wc,
    const float* __restrict__ Gm, u64* __restrict__ Bmask,
    u64* __restrict__ Brow, const u64* __restrict__ Ymask) {
  __shared__ float sW[6400];   // [c][i], i contiguous
  __shared__ float sG[4096];   // [i][k]
  for (int t = threadIdx.x; t < 6400; t += 256) sW[t] = Wc[t];
  for (int t = threadIdx.x; t < 4096; t += 256) sG[t] = Gm[t];
  __syncthreads();
  int g = blockIdx.x * 4 + (threadIdx.x >> 6);
  int lane = threadIdx.x & 63;
  if (g >= NGRP) return;
  int j = g * 64 + lane;
  bool act = j < NT;
  int jc = act ? j : NT - 1;
  int ow = owner[jc];
  float p[64];
  if (ow >= 0) {
#pragma unroll
    for (int i = 0; i < 64; ++i) p[i] = ETA_MU * u[ow * 64 + i];
  } else {
#pragma unroll
    for (int i = 0; i < 64; ++i) p[i] = ETA_MU * U[(size_t)i * NT + jc];
  }
  u64 y0 = Ymask[2 * jc], y1 = Ymask[2 * jc + 1];
  for (int c = 0; c < 100; ++c) {
    u64 w = (c < 64) ? y0 : y1;
    float yb = (float)((w >> (c & 63)) & 1ull);
    const float4* wr = (const float4*)&sW[c * 64];
#pragma unroll
    for (int q = 0; q < 16; ++q) {
      float4 wvv = wr[q];
      p[4 * q + 0] += wvv.x * yb;
      p[4 * q + 1] += wvv.y * yb;
      p[4 * q + 2] += wvv.z * yb;
      p[4 * q + 3] += wvv.w * yb;
    }
  }
  u64 bm = Bmask[jc];
  float bf[64];
#pragma unroll
  for (int k = 0; k < 64; ++k) bf[k] = ((bm >> k) & 1ull) ? 1.0f : -1.0f;
#pragma unroll
  for (int i = 0; i < 64; ++i) {
    const float4* gr = (const float4*)&sG[i * 64];
    float d0 = 0.f, d1 = 0.f, d2 = 0.f, d3 = 0.f;
#pragma unroll
    for (int q = 0; q < 16; ++q) {
      float4 gv = gr[q];
      d0 += gv.x * bf[4 * q + 0];
      d1 += gv.y * bf[4 * q + 1];
      d2 += gv.z * bf[4 * q + 2];
      d3 += gv.w * bf[4 * q + 3];
    }
    float val = p[i] - ((d0 + d1) + (d2 + d3)) + sG[i * 64 + i] * bf[i];
    bf[i] = (val > 0.0f) ? 1.0f : -1.0f;
  }
  u64 nm = 0;
#pragma unroll
  for (int k = 0; k < 64; ++k)
    if (bf[k] > 0.0f) nm |= 1ull << k;
  if (!act) nm = 0;
  if (act) Bmask[j] = nm;
  u64 tb = transpose64(nm, lane);
  Brow[(size_t)lane * WPR + g] = tb;
}

// L1: likelihood sum over 128 x 100000
__global__ __launch_bounds__(256) void l1_like(
    const float* __restrict__ U, const float* __restrict__ u,
    const int* __restrict__ owner, const u64* __restrict__ Ymask,
    const u64* __restrict__ ybatch, double* __restrict__ acc) {
  __shared__ float su[8192];
  __shared__ u64 sy[256];
  for (int t = threadIdx.x; t < 8192; t += 256) su[t] = u[t];
  if (threadIdx.x < 256) sy[threadIdx.x] = ybatch[threadIdx.x];
  __syncthreads();
  int g = blockIdx.x * 4 + (threadIdx.x >> 6);
  int lane = threadIdx.x & 63;
  double lsum = 0.0;
  if (g < NGRP) {
    int j = g * 64 + lane;
    if (j < NT) {
      float uc[64];
      int ow = owner[j];
      if (ow >= 0) {
#pragma unroll
        for (int i = 0; i < 64; ++i) uc[i] = su[ow * 64 + i];
      } else {
#pragma unroll
        for (int i = 0; i < 64; ++i) uc[i] = U[(size_t)i * NT + j];
      }
      u64 y0 = Ymask[2 * j], y1 = Ymask[2 * j + 1];
      for (int b = 0; b < 128; ++b) {
        const float4* ub = (const float4*)&su[b * 64];
        float d0 = 0.f, d1 = 0.f, d2 = 0.f, d3 = 0.f;
#pragma unroll
        for (int q = 0; q < 16; ++q) {
          float4 uv = ub[q];
          d0 += uv.x * uc[4 * q + 0];
          d1 += uv.y * uc[4 * q + 1];
          d2 += uv.z * uc[4 * q + 2];
          d3 += uv.w * uc[4 * q + 3];
        }
        float ip = 0.5f * ((d0 + d1) + (d2 + d3));
        bool s = ((sy[2 * b] & y0) | (sy[2 * b + 1] & y1)) != 0ull;
        float a = fabsf(ip);
        float like = __logf(1.0f + __expf(-a)) + fmaxf(ip, 0.0f) - (s ? ip : 0.0f);
        lsum += (double)like;
      }
    }
  }
  lsum = wave_reduce_f64(lsum);
  if (lane == 0) atomicAdd(&acc[0], lsum);
}

// L2: cl_loss sum of squares + reg sum
__global__ __launch_bounds__(256) void l2_cl(
    const float* __restrict__ Wr, const float* __restrict__ y,
    const int* __restrict__ ind, const u64* __restrict__ Bmask,
    double* __restrict__ acc) {
  __shared__ float sw[6400];   // W[i*100+c]
  __shared__ u64 sbm[128];
  for (int t = threadIdx.x; t < 6400; t += 256) sw[t] = Wr[t];
  if (threadIdx.x < 128) sbm[threadIdx.x] = Bmask[ind[threadIdx.x]];
  __syncthreads();
  double cls = 0.0, regs = 0.0;
  for (int e = threadIdx.x; e < 12800; e += 256) {
    int c = e >> 7, b = e & 127;
    u64 bm = sbm[b];
    float s = 0.0f;
#pragma unroll
    for (int i = 0; i < 64; ++i) {
      float w = sw[i * 100 + c];
      s += ((bm >> i) & 1ull) ? w : -w;
    }
    float d = y[b * 100 + c] - s;
    cls += (double)(d * d);
  }
  for (int e = threadIdx.x; e < 6400; e += 256) {
    float w = sw[e];
    regs += (double)(w * w);
  }
  cls = wave_reduce_f64(cls);
  regs = wave_reduce_f64(regs);
  if ((threadIdx.x & 63) == 0) {
    atomicAdd(&acc[1], cls);
    atomicAdd(&acc[2], regs);
  }
}

__global__ void fin(const double* __restrict__ acc, float* __restrict__ out) {
  // mean(like)/(128*100000) + MU*mean(cl)/12800 + NU*mean(W^2)/6400
  out[0] = (float)(acc[0] * (1.0 / 12800000.0) + acc[1] * (1.0 / 12800.0) +
                   acc[2] * (0.1 / 6400.0));
}

extern "C" void kernel_launch(void* const* d_in, const int* in_sizes, int n_in,
                              void* d_out, int out_size, void* d_ws, size_t ws_size,
                              hipStream_t stream) {
  const float* u    = (const float*)d_in[0];
  const float* y    = (const float*)d_in[1];
  const int*   ind  = (const int*)d_in[2];
  const float* U    = (const float*)d_in[3];
  const float* B    = (const float*)d_in[4];
  const float* Ybuf = (const float*)d_in[5];
  char* ws = (char*)d_ws;
  double* acc   = (double*)(ws + 0);
  u64* Bmask    = (u64*)(ws + 256);
  u64* Ymask    = (u64*)(ws + 800256);
  u64* Brow     = (u64*)(ws + 2400256);
  u64* Yrow     = (u64*)(ws + 3203072);
  u64* ybatch   = (u64*)(ws + 4457472);
  int* popcY    = (int*)(ws + 4459520);
  int* S_part   = (int*)(ws + 4460032);
  int* R_part   = (int*)(ws + 4525568);
  float* Wr     = (float*)(ws + 4627968);
  float* Wc     = (float*)(ws + 4653568);
  float* G      = (float*)(ws + 4679168);
  int* owner    = (int*)(ws + 4695552);

  init_acc<<<1, 64, 0, stream>>>(acc);
  build_colmasks<<<(NT + 255) / 256, 256, 0, stream>>>(B, Ybuf, Bmask, Ymask, owner);
  scatter_y<<<1, 128, 0, stream>>>(y, ind, Ymask, ybatch, owner);
  build_rows<<<391, 256, 0, stream>>>(Bmask, Ymask, Brow, Yrow);
  popcY_k<<<1, 128, 0, stream>>>(Yrow, popcY);
  for (int it = 0; it < 10; ++it) {
    k1_sr<<<dim3(64, 4), 256, 0, stream>>>(Brow, Yrow, S_part, R_part);
    k2_solve<<<1, 256, 0, stream>>>(S_part, R_part, popcY, Wr, Wc, G);
    k3_gs<<<391, 256, 0, stream>>>(U, u, owner, Wc, G, Bmask, Brow, Ymask);
  }
  l1_like<<<391, 256, 0, stream>>>(U, u, owner, Ymask, ybatch, acc);
  l2_cl<<<1, 256, 0, stream>>>(Wr, y, ind, Bmask, acc);
  fin<<<1, 1, 0, stream>>>(acc, (float*)d_out);
}

// Round 2
// 2806.882 us; speedup vs baseline: 1.1053x; 1.1053x over previous
//
#include <hip/hip_runtime.h>
#include <cstdint>
#include <cstddef>

// DSDHLoss: faithful DCC loop on bitmask representation.
// B (+-1) -> 64-bit column masks + row-major bit-planes; Ybuf (0/1) -> masks.
// S=B B^T and R=B Y^T via popcount (exact integers == fp32 reference values).
// k2: Gauss-Jordan on [A|R] in LDS (no register x[] -> no scratch spill).
// k3/l1: wave-uniform operands read from global (s_load path), not LDS.

#define NT 100000
#define WPR 1568      // padded u64 words per bit-row
#define NWREAL 1563   // ceil(100000/64)
#define NGRP 1563
#define ETA_MU 55.0f
#define LAM 0.1f
#define AW 168        // augmented width: 64 (A) + 100 (R) + 4 pad

typedef unsigned long long u64;

__device__ inline u64 transpose64(u64 x, int lane) {
  const u64 ms[6] = {0x5555555555555555ull,0x3333333333333333ull,0x0F0F0F0F0F0F0F0Full,
                     0x00FF00FF00FF00FFull,0x0000FFFF0000FFFFull,0x00000000FFFFFFFFull};
#pragma unroll
  for (int si = 0; si < 6; ++si) {
    int s = 1 << si;
    u64 m = ms[si];
    u64 y = __shfl_xor(x, s, 64);
    if ((lane & s) == 0) x = (x & m) | ((y & m) << s);
    else                 x = (x & ~m) | ((y & ~m) >> s);
  }
  return x;
}

__device__ inline int wave_reduce_i32(int v) {
#pragma unroll
  for (int off = 32; off > 0; off >>= 1) v += __shfl_down(v, off, 64);
  return v;
}
__device__ inline double wave_reduce_f64(double v) {
#pragma unroll
  for (int off = 32; off > 0; off >>= 1) v += __shfl_down(v, off, 64);
  return v;
}

__global__ void init_acc(double* acc) {
  if (threadIdx.x < 4) acc[threadIdx.x] = 0.0;
}

// column masks for B and Ybuf; owner[] = -1 everywhere (scatter fills later)
__global__ __launch_bounds__(256) void build_colmasks(
    const float* __restrict__ B, const float* __restrict__ Ybuf,
    u64* __restrict__ Bmask, u64* __restrict__ Ymask, int* __restrict__ owner) {
  int j = blockIdx.x * 256 + threadIdx.x;
  if (j >= NT) return;
  owner[j] = -1;
  u64 bm = 0;
#pragma unroll
  for (int i = 0; i < 64; ++i)
    bm |= ((u64)(B[(size_t)i * NT + j] > 0.0f)) << i;
  u64 m0 = 0, m1 = 0;
#pragma unroll
  for (int c = 0; c < 64; ++c)
    m0 |= ((u64)(Ybuf[(size_t)c * NT + j] > 0.5f)) << c;
#pragma unroll
  for (int c = 64; c < 100; ++c)
    m1 |= ((u64)(Ybuf[(size_t)c * NT + j] > 0.5f)) << (c - 64);
  Bmask[j] = bm;
  Ymask[2 * j] = m0;
  Ymask[2 * j + 1] = m1;
}

// scatter: Ybuf[:, ind[b]] = y[b]; owner[ind[b]] = b; also batch y-masks
__global__ void scatter_y(const float* __restrict__ y, const int* __restrict__ ind,
                          u64* __restrict__ Ymask, u64* __restrict__ ybatch,
                          int* __restrict__ owner) {
  int b = threadIdx.x;
  if (b >= 128) return;
  u64 m0 = 0, m1 = 0;
  for (int c = 0; c < 100; ++c) {
    bool v = y[b * 100 + c] > 0.5f;
    if (c < 64) m0 |= ((u64)v) << c;
    else        m1 |= ((u64)v) << (c - 64);
  }
  ybatch[2 * b] = m0;
  ybatch[2 * b + 1] = m1;
  int col = ind[b];
  Ymask[2 * col] = m0;
  Ymask[2 * col + 1] = m1;
  owner[col] = b;
}

// column masks -> row-major bit planes (wave-level 64x64 bit transpose)
__global__ __launch_bounds__(256) void build_rows(
    const u64* __restrict__ Bmask, const u64* __restrict__ Ymask,
    u64* __restrict__ Brow, u64* __restrict__ Yrow) {
  int g = blockIdx.x * 4 + (threadIdx.x >> 6);
  int lane = threadIdx.x & 63;
  if (g >= NGRP) return;
  int j = g * 64 + lane;
  bool act = j < NT;
  u64 bm = act ? Bmask[j] : 0ull;
  u64 y0 = act ? Ymask[2 * j] : 0ull;
  u64 y1 = act ? Ymask[2 * j + 1] : 0ull;
  u64 tb = transpose64(bm, lane);
  Brow[(size_t)lane * WPR + g] = tb;
  u64 t0 = transpose64(y0, lane);
  Yrow[(size_t)lane * WPR + g] = t0;
  u64 t1 = transpose64(y1, lane);
  if (lane < 36) Yrow[(size_t)(64 + lane) * WPR + g] = t1;
}

__global__ void popcY_k(const u64* __restrict__ Yrow, int* __restrict__ popcY) {
  int c = threadIdx.x;
  if (c >= 100) return;
  int s = 0;
  for (int w = 0; w < NWREAL; ++w) s += __popcll(Yrow[(size_t)c * WPR + w]);
  popcY[c] = s;
}

// K1: partial mismatch counts for S and AND-counts for R, per word-quarter
__global__ __launch_bounds__(256) void k1_sr(
    const u64* __restrict__ Brow, const u64* __restrict__ Yrow,
    int* __restrict__ S_part, int* __restrict__ R_part) {
  int k = blockIdx.x, q = blockIdx.y;
  __shared__ u64 sb[392];
  int w0 = q * 392;
  int nw = NWREAL - w0; if (nw > 392) nw = 392;
  for (int t = threadIdx.x; t < nw; t += 256) sb[t] = Brow[(size_t)k * WPR + w0 + t];
  __syncthreads();
  int wv = threadIdx.x >> 6, lane = threadIdx.x & 63;
  for (int l = wv; l < 64; l += 4) {
    const u64* br = Brow + (size_t)l * WPR + w0;
    int s = 0;
    for (int t = lane; t < nw; t += 64) s += __popcll(sb[t] ^ br[t]);
    s = wave_reduce_i32(s);
    if (lane == 0) S_part[q * 4096 + k * 64 + l] = s;
  }
  for (int c = wv; c < 100; c += 4) {
    const u64* yr = Yrow + (size_t)c * WPR + w0;
    int s = 0;
    for (int t = lane; t < nw; t += 64) s += __popcll(sb[t] & yr[t]);
    s = wave_reduce_i32(s);
    if (lane == 0) R_part[q * 6400 + k * 100 + c] = s;
  }
}

// K2: Gauss-Jordan on augmented [A | R] (64 x 168) fully in LDS.
// A = (NT - 2*mismatch) + LAM*I; R = 2*and - popcY. After 64 pivot steps
// cols 64..163 hold X = A^-1 R. Then G = X X^T via stride-100 LDS copy.
__global__ __launch_bounds__(256) void k2_solve(
    const int* __restrict__ S_part, const int* __restrict__ R_part,
    const int* __restrict__ popcY, float* __restrict__ Wr,
    float* __restrict__ Wc, float* __restrict__ G) {
  __shared__ float M[64 * AW];
  __shared__ float rowj[AW];
  __shared__ float colj[64];
  __shared__ float X2[64 * 100];
  int tid = threadIdx.x;
  int wv = tid >> 6, lane = tid & 63;
  for (int e = tid; e < 4096; e += 256) {
    int k = e >> 6, l = e & 63;
    int mm = S_part[e] + S_part[4096 + e] + S_part[8192 + e] + S_part[12288 + e];
    float v = (float)(NT - 2 * mm);
    if (k == l) v += LAM;
    M[k * AW + l] = v;
  }
  for (int e = tid; e < 6400; e += 256) {
    int k = e / 100, c = e - k * 100;
    int rr = R_part[e] + R_part[6400 + e] + R_part[12800 + e] + R_part[19200 + e];
    M[k * AW + 64 + c] = (float)(2 * rr - popcY[c]);
  }
  for (int e = tid; e < 256; e += 256) {
    int k = e >> 2, t = 164 + (e & 3);
    M[k * AW + t] = 0.0f;
  }
  for (int j = 0; j < 64; ++j) {
    __syncthreads();
    if (tid < AW) {
      float pv = 1.0f / M[j * AW + j];
      float v = M[j * AW + tid] * pv;
      rowj[tid] = v;
      M[j * AW + tid] = v;
    } else if (tid >= 192) {
      int k = tid - 192;
      colj[k] = (k == j) ? 0.0f : M[k * AW + j];
    }
    __syncthreads();
    int base = (j + 1) & ~3;
    int t = base + 4 * lane;
    if (t < AW) {
      float4 r = *(const float4*)&rowj[t];
      for (int k = wv; k < 64; k += 4) {
        float c = colj[k];
        float4 m = *(float4*)&M[(size_t)k * AW + t];
        m.x -= c * r.x; m.y -= c * r.y; m.z -= c * r.z; m.w -= c * r.w;
        *(float4*)&M[(size_t)k * AW + t] = m;
      }
    }
  }
  __syncthreads();
  for (int e = tid; e < 6400; e += 256) {
    int k = e / 100, c = e - (e / 100) * 100;
    float v = M[k * AW + 64 + c];
    Wr[k * 100 + c] = v;
    Wc[c * 64 + k] = v;
    X2[k * 100 + c] = v;
  }
  __syncthreads();
  for (int e = tid; e < 4096; e += 256) {
    int i = e >> 6, l = e & 63;   // i wave-uniform (broadcast), l = lane
    const float4* xi = (const float4*)&X2[i * 100];
    const float4* xl = (const float4*)&X2[l * 100];
    float d0 = 0.f, d1 = 0.f, d2 = 0.f, d3 = 0.f;
#pragma unroll
    for (int q = 0; q < 25; ++q) {
      float4 a = xi[q], b = xl[q];
      d0 += a.x * b.x; d1 += a.y * b.y; d2 += a.z * b.z; d3 += a.w * b.w;
    }
    G[e] = (d0 + d1) + (d2 + d3);
  }
}

// K3: per-column P = W@Ybuf_col (sparse over set classes) + 55*U_col, then
// exact sequential GS sign sweep reading G from GLOBAL with wave-uniform
// addresses (s_load path; no LDS for G).
__global__ __launch_bounds__(256) void k3_gs(
    const float* __restrict__ U, const float* __restrict__ u,
    const int* __restrict__ owner, const float* __restrict__ Wc,
    const float* __restrict__ Gm, u64* __restrict__ Bmask,
    u64* __restrict__ Brow, const u64* __restrict__ Ymask) {
  __shared__ float sW[100 * 68];   // [c][i], stride 68 (bank-spread for lane-varying c)
  for (int t = threadIdx.x; t < 6400; t += 256) {
    int c = t >> 6, i = t & 63;
    sW[c * 68 + i] = Wc[t];
  }
  __syncthreads();
  int g = blockIdx.x * 4 + (threadIdx.x >> 6);
  int lane = threadIdx.x & 63;
  if (g >= NGRP) return;
  int j = g * 64 + lane;
  bool act = j < NT;
  int jc = act ? j : NT - 1;
  int ow = owner[jc];
  float p[64];
  if (ow >= 0) {
#pragma unroll
    for (int i = 0; i < 64; ++i) p[i] = ETA_MU * u[ow * 64 + i];
  } else {
#pragma unroll
    for (int i = 0; i < 64; ++i) p[i] = ETA_MU * U[(size_t)i * NT + jc];
  }
  u64 y0 = Ymask[2 * jc], y1 = Ymask[2 * jc + 1];
  // sparse accumulation: identical fp32 result (skipped terms add exactly 0),
  // same ascending-c order as dense
  u64 mm = y0;
  while (mm) {
    int c = __builtin_ctzll(mm); mm &= mm - 1;
    const float4* wr = (const float4*)&sW[c * 68];
#pragma unroll
    for (int q = 0; q < 16; ++q) {
      float4 wvv = wr[q];
      p[4 * q + 0] += wvv.x; p[4 * q + 1] += wvv.y;
      p[4 * q + 2] += wvv.z; p[4 * q + 3] += wvv.w;
    }
  }
  mm = y1;
  while (mm) {
    int c = 64 + __builtin_ctzll(mm); mm &= mm - 1;
    const float4* wr = (const float4*)&sW[c * 68];
#pragma unroll
    for (int q = 0; q < 16; ++q) {
      float4 wvv = wr[q];
      p[4 * q + 0] += wvv.x; p[4 * q + 1] += wvv.y;
      p[4 * q + 2] += wvv.z; p[4 * q + 3] += wvv.w;
    }
  }
  u64 bm = Bmask[jc];
  float bf[64];
#pragma unroll
  for (int k = 0; k < 64; ++k) bf[k] = ((bm >> k) & 1ull) ? 1.0f : -1.0f;
#pragma unroll
  for (int i = 0; i < 64; ++i) {
    const float* gr = &Gm[i * 64];   // wave-uniform address -> scalar loads
    float d0 = 0.f, d1 = 0.f, d2 = 0.f, d3 = 0.f;
#pragma unroll
    for (int q = 0; q < 16; ++q) {
      d0 += gr[4 * q + 0] * bf[4 * q + 0];
      d1 += gr[4 * q + 1] * bf[4 * q + 1];
      d2 += gr[4 * q + 2] * bf[4 * q + 2];
      d3 += gr[4 * q + 3] * bf[4 * q + 3];
    }
    float val = p[i] - ((d0 + d1) + (d2 + d3)) + gr[i] * bf[i];
    bf[i] = (val > 0.0f) ? 1.0f : -1.0f;
  }
  u64 nm = 0;
#pragma unroll
  for (int k = 0; k < 64; ++k)
    if (bf[k] > 0.0f) nm |= 1ull << k;
  if (!act) nm = 0;
  if (act) Bmask[j] = nm;
  u64 tb = transpose64(nm, lane);
  Brow[(size_t)lane * WPR + g] = tb;
}

// L1: likelihood sum over 128 x 100000; u/ybatch read with wave-uniform
// addresses (scalar path), per-column U in VGPRs.
__global__ __launch_bounds__(256) void l1_like(
    const float* __restrict__ U, const float* __restrict__ u,
    const int* __restrict__ owner, const u64* __restrict__ Ymask,
    const u64* __restrict__ ybatch, double* __restrict__ acc) {
  int g = blockIdx.x * 4 + (threadIdx.x >> 6);
  int lane = threadIdx.x & 63;
  double lsum = 0.0;
  if (g < NGRP) {
    int j = g * 64 + lane;
    if (j < NT) {
      float uc[64];
      int ow = owner[j];
      if (ow >= 0) {
#pragma unroll
        for (int i = 0; i < 64; ++i) uc[i] = u[ow * 64 + i];
      } else {
#pragma unroll
        for (int i = 0; i < 64; ++i) uc[i] = U[(size_t)i * NT + j];
      }
      u64 y0 = Ymask[2 * j], y1 = Ymask[2 * j + 1];
      for (int b = 0; b < 128; ++b) {
        const float* ub = &u[b * 64];   // wave-uniform -> scalar loads
        float d0 = 0.f, d1 = 0.f, d2 = 0.f, d3 = 0.f;
#pragma unroll
        for (int q = 0; q < 16; ++q) {
          d0 += ub[4 * q + 0] * uc[4 * q + 0];
          d1 += ub[4 * q + 1] * uc[4 * q + 1];
          d2 += ub[4 * q + 2] * uc[4 * q + 2];
          d3 += ub[4 * q + 3] * uc[4 * q + 3];
        }
        float ip = 0.5f * ((d0 + d1) + (d2 + d3));
        bool s = ((ybatch[2 * b] & y0) | (ybatch[2 * b + 1] & y1)) != 0ull;
        float a = fabsf(ip);
        float like = __logf(1.0f + __expf(-a)) + fmaxf(ip, 0.0f) - (s ? ip : 0.0f);
        lsum += (double)like;
      }
    }
  }
  lsum = wave_reduce_f64(lsum);
  if (lane == 0) atomicAdd(&acc[0], lsum);
}

// L2: cl_loss sum of squares + reg sum
__global__ __launch_bounds__(256) void l2_cl(
    const float* __restrict__ Wr, const float* __restrict__ y,
    const int* __restrict__ ind, const u64* __restrict__ Bmask,
    double* __restrict__ acc) {
  __shared__ float sw[6400];   // W[i*100+c]
  __shared__ u64 sbm[128];
  for (int t = threadIdx.x; t < 6400; t += 256) sw[t] = Wr[t];
  if (threadIdx.x < 128) sbm[threadIdx.x] = Bmask[ind[threadIdx.x]];
  __syncthreads();
  double cls = 0.0, regs = 0.0;
  for (int e = threadIdx.x; e < 12800; e += 256) {
    int c = e >> 7, b = e & 127;
    u64 bm = sbm[b];
    float s = 0.0f;
#pragma unroll
    for (int i = 0; i < 64; ++i) {
      float w = sw[i * 100 + c];
      s += ((bm >> i) & 1ull) ? w : -w;
    }
    float d = y[b * 100 + c] - s;
    cls += (double)(d * d);
  }
  for (int e = threadIdx.x; e < 6400; e += 256) {
    float w = sw[e];
    regs += (double)(w * w);
  }
  cls = wave_reduce_f64(cls);
  regs = wave_reduce_f64(regs);
  if ((threadIdx.x & 63) == 0) {
    atomicAdd(&acc[1], cls);
    atomicAdd(&acc[2], regs);
  }
}

__global__ void fin(const double* __restrict__ acc, float* __restrict__ out) {
  out[0] = (float)(acc[0] * (1.0 / 12800000.0) + acc[1] * (1.0 / 12800.0) +
                   acc[2] * (0.1 / 6400.0));
}

extern "C" void kernel_launch(void* const* d_in, const int* in_sizes, int n_in,
                              void* d_out, int out_size, void* d_ws, size_t ws_size,
                              hipStream_t stream) {
  const float* u    = (const float*)d_in[0];
  const float* y    = (const float*)d_in[1];
  const int*   ind  = (const int*)d_in[2];
  const float* U    = (const float*)d_in[3];
  const float* B    = (const float*)d_in[4];
  const float* Ybuf = (const float*)d_in[5];
  char* ws = (char*)d_ws;
  double* acc   = (double*)(ws + 0);
  u64* Bmask    = (u64*)(ws + 256);
  u64* Ymask    = (u64*)(ws + 800256);
  u64* Brow     = (u64*)(ws + 2400256);
  u64* Yrow     = (u64*)(ws + 3203072);
  u64* ybatch   = (u64*)(ws + 4457472);
  int* popcY    = (int*)(ws + 4459520);
  int* S_part   = (int*)(ws + 4460032);
  int* R_part   = (int*)(ws + 4525568);
  float* Wr     = (float*)(ws + 4627968);
  float* Wc     = (float*)(ws + 4653568);
  float* G      = (float*)(ws + 4679168);
  int* owner    = (int*)(ws + 4695552);

  init_acc<<<1, 64, 0, stream>>>(acc);
  build_colmasks<<<(NT + 255) / 256, 256, 0, stream>>>(B, Ybuf, Bmask, Ymask, owner);
  scatter_y<<<1, 128, 0, stream>>>(y, ind, Ymask, ybatch, owner);
  build_rows<<<391, 256, 0, stream>>>(Bmask, Ymask, Brow, Yrow);
  popcY_k<<<1, 128, 0, stream>>>(Yrow, popcY);
  for (int it = 0; it < 10; ++it) {
    k1_sr<<<dim3(64, 4), 256, 0, stream>>>(Brow, Yrow, S_part, R_part);
    k2_solve<<<1, 256, 0, stream>>>(S_part, R_part, popcY, Wr, Wc, G);
    k3_gs<<<391, 256, 0, stream>>>(U, u, owner, Wc, G, Bmask, Brow, Ymask);
  }
  l1_like<<<391, 256, 0, stream>>>(U, u, owner, Ymask, ybatch, acc);
  l2_cl<<<1, 256, 0, stream>>>(Wr, y, ind, Bmask, acc);
  fin<<<1, 1, 0, stream>>>(acc, (float*)d_out);
}

// Round 3
// 2422.656 us; speedup vs baseline: 1.2806x; 1.1586x over previous
//
#include <hip/hip_runtime.h>
#include <cstdint>
#include <cstddef>

// DSDHLoss: faithful DCC loop on bitmask representation.
// B (+-1) -> 64-bit column masks + row-major bit-planes; Ybuf (0/1) -> masks.
// S=B B^T and R=B Y^T via popcount (exact integers == fp32 reference values).
// k2: A = (NT+lam) I + E (diag(S)=NT exactly). Solve X=A^-1 R by scalar-
//     preconditioned Neumann iteration, ||alpha E|| ~ 0.05 -> 6 iters hits
//     fp32 fixed point. E as swizzled i16 in LDS; X double-buffered stride
//     100 (conflict-free b128); R in registers. G = X X^T in epilogue.

#define NT 100000
#define WPR 1568      // padded u64 words per bit-row
#define NWREAL 1563   // ceil(100000/64)
#define NGRP 1563
#define ETA_MU 55.0f
#define LAM 0.1f

typedef unsigned long long u64;

__device__ inline u64 transpose64(u64 x, int lane) {
  const u64 ms[6] = {0x5555555555555555ull,0x3333333333333333ull,0x0F0F0F0F0F0F0F0Full,
                     0x00FF00FF00FF00FFull,0x0000FFFF0000FFFFull,0x00000000FFFFFFFFull};
#pragma unroll
  for (int si = 0; si < 6; ++si) {
    int s = 1 << si;
    u64 m = ms[si];
    u64 y = __shfl_xor(x, s, 64);
    if ((lane & s) == 0) x = (x & m) | ((y & m) << s);
    else                 x = (x & ~m) | ((y & ~m) >> s);
  }
  return x;
}

__device__ inline int wave_reduce_i32(int v) {
#pragma unroll
  for (int off = 32; off > 0; off >>= 1) v += __shfl_down(v, off, 64);
  return v;
}
__device__ inline double wave_reduce_f64(double v) {
#pragma unroll
  for (int off = 32; off > 0; off >>= 1) v += __shfl_down(v, off, 64);
  return v;
}

__global__ void init_acc(double* acc) {
  if (threadIdx.x < 4) acc[threadIdx.x] = 0.0;
}

// column masks for B and Ybuf; owner[] = -1 everywhere (scatter fills later)
__global__ __launch_bounds__(256) void build_colmasks(
    const float* __restrict__ B, const float* __restrict__ Ybuf,
    u64* __restrict__ Bmask, u64* __restrict__ Ymask, int* __restrict__ owner) {
  int j = blockIdx.x * 256 + threadIdx.x;
  if (j >= NT) return;
  owner[j] = -1;
  u64 bm = 0;
#pragma unroll
  for (int i = 0; i < 64; ++i)
    bm |= ((u64)(B[(size_t)i * NT + j] > 0.0f)) << i;
  u64 m0 = 0, m1 = 0;
#pragma unroll
  for (int c = 0; c < 64; ++c)
    m0 |= ((u64)(Ybuf[(size_t)c * NT + j] > 0.5f)) << c;
#pragma unroll
  for (int c = 64; c < 100; ++c)
    m1 |= ((u64)(Ybuf[(size_t)c * NT + j] > 0.5f)) << (c - 64);
  Bmask[j] = bm;
  Ymask[2 * j] = m0;
  Ymask[2 * j + 1] = m1;
}

// scatter: Ybuf[:, ind[b]] = y[b]; owner[ind[b]] = b; also batch y-masks
__global__ void scatter_y(const float* __restrict__ y, const int* __restrict__ ind,
                          u64* __restrict__ Ymask, u64* __restrict__ ybatch,
                          int* __restrict__ owner) {
  int b = threadIdx.x;
  if (b >= 128) return;
  u64 m0 = 0, m1 = 0;
  for (int c = 0; c < 100; ++c) {
    bool v = y[b * 100 + c] > 0.5f;
    if (c < 64) m0 |= ((u64)v) << c;
    else        m1 |= ((u64)v) << (c - 64);
  }
  ybatch[2 * b] = m0;
  ybatch[2 * b + 1] = m1;
  int col = ind[b];
  Ymask[2 * col] = m0;
  Ymask[2 * col + 1] = m1;
  owner[col] = b;
}

// column masks -> row-major bit planes (wave-level 64x64 bit transpose)
__global__ __launch_bounds__(256) void build_rows(
    const u64* __restrict__ Bmask, const u64* __restrict__ Ymask,
    u64* __restrict__ Brow, u64* __restrict__ Yrow) {
  int g = blockIdx.x * 4 + (threadIdx.x >> 6);
  int lane = threadIdx.x & 63;
  if (g >= NGRP) return;
  int j = g * 64 + lane;
  bool act = j < NT;
  u64 bm = act ? Bmask[j] : 0ull;
  u64 y0 = act ? Ymask[2 * j] : 0ull;
  u64 y1 = act ? Ymask[2 * j + 1] : 0ull;
  u64 tb = transpose64(bm, lane);
  Brow[(size_t)lane * WPR + g] = tb;
  u64 t0 = transpose64(y0, lane);
  Yrow[(size_t)lane * WPR + g] = t0;
  u64 t1 = transpose64(y1, lane);
  if (lane < 36) Yrow[(size_t)(64 + lane) * WPR + g] = t1;
}

// popcY: one block per class, parallel popc over the bit-row
__global__ __launch_bounds__(256) void popcY_k(const u64* __restrict__ Yrow,
                                               int* __restrict__ popcY) {
  int c = blockIdx.x;
  __shared__ int red[4];
  int s = 0;
  for (int w = threadIdx.x; w < NWREAL; w += 256)
    s += __popcll(Yrow[(size_t)c * WPR + w]);
  s = wave_reduce_i32(s);
  if ((threadIdx.x & 63) == 0) red[threadIdx.x >> 6] = s;
  __syncthreads();
  if (threadIdx.x == 0) popcY[c] = red[0] + red[1] + red[2] + red[3];
}

// K1: partial mismatch counts for S and AND-counts for R, per word-quarter
__global__ __launch_bounds__(256) void k1_sr(
    const u64* __restrict__ Brow, const u64* __restrict__ Yrow,
    int* __restrict__ S_part, int* __restrict__ R_part) {
  int k = blockIdx.x, q = blockIdx.y;
  __shared__ u64 sb[392];
  int w0 = q * 392;
  int nw = NWREAL - w0; if (nw > 392) nw = 392;
  for (int t = threadIdx.x; t < nw; t += 256) sb[t] = Brow[(size_t)k * WPR + w0 + t];
  __syncthreads();
  int wv = threadIdx.x >> 6, lane = threadIdx.x & 63;
  for (int l = wv; l < 64; l += 4) {
    const u64* br = Brow + (size_t)l * WPR + w0;
    int s = 0;
    for (int t = lane; t < nw; t += 64) s += __popcll(sb[t] ^ br[t]);
    s = wave_reduce_i32(s);
    if (lane == 0) S_part[q * 4096 + k * 64 + l] = s;
  }
  for (int c = wv; c < 100; c += 4) {
    const u64* yr = Yrow + (size_t)c * WPR + w0;
    int s = 0;
    for (int t = lane; t < nw; t += 64) s += __popcll(sb[t] & yr[t]);
    s = wave_reduce_i32(s);
    if (lane == 0) R_part[q * 6400 + k * 100 + c] = s;
  }
}

// K2: Neumann solve X = A^-1 R with A = (NT+LAM) I + E.
// X_{m+1} = alpha (R - E X_m), alpha = 1/(NT+LAM). 6 iterations.
// Epilogue: Wr/Wc stores + G = X X^T.
__global__ __launch_bounds__(256) void k2_solve(
    const int* __restrict__ S_part, const int* __restrict__ R_part,
    const int* __restrict__ popcY, float* __restrict__ Wr,
    float* __restrict__ Wc, float* __restrict__ G) {
  __shared__ short sEi[64 * 64];   // [k][l] at k*64 + (l ^ (k&31)), values exact
  __shared__ float sXa[64 * 100];  // stride 100: b128 lane-vector reads conflict-free
  __shared__ float sXb[64 * 100];
  int tid = threadIdx.x;
  int wv = tid >> 6, k = tid & 63;
  const float alpha = 1.0f / (100000.0f + LAM);
  // E setup (exact int16; |E| ~ +-1500 for sign-of-normal rows)
  for (int e = tid; e < 4096; e += 256) {
    int kk = e >> 6, ll = e & 63;
    int mm = S_part[e] + S_part[4096 + e] + S_part[8192 + e] + S_part[12288 + e];
    int v = (kk == ll) ? 0 : (NT - 2 * mm);
    v = v > 32767 ? 32767 : (v < -32767 ? -32767 : v);
    sEi[kk * 64 + (ll ^ (kk & 31))] = (short)v;
  }
  // R into registers (wave chunks {28,24,24,24}, 16B-aligned), X0 = alpha*R
  int c0 = (wv == 0) ? 0 : (4 + wv * 24);   // 0,28,52,76
  int cq = (wv == 0) ? 7 : 6;               // quads per wave
  float4 rr4[7];
#pragma unroll
  for (int q = 0; q < 7; ++q) {
    if (q < cq) {
      float tmp[4];
#pragma unroll
      for (int e4 = 0; e4 < 4; ++e4) {
        int c = c0 + 4 * q + e4;
        int e = k * 100 + c;
        int rr = R_part[e] + R_part[6400 + e] + R_part[12800 + e] + R_part[19200 + e];
        tmp[e4] = (float)(2 * rr - popcY[c]);
      }
      rr4[q] = make_float4(tmp[0], tmp[1], tmp[2], tmp[3]);
      float4 x0 = make_float4(alpha * tmp[0], alpha * tmp[1], alpha * tmp[2], alpha * tmp[3]);
      *(float4*)&sXa[k * 100 + c0 + 4 * q] = x0;
    }
  }
  __syncthreads();
  float* Xs = sXa;
  float* Xd = sXb;
  for (int it = 0; it < 6; ++it) {
    float4 a4[7];
#pragma unroll
    for (int q = 0; q < 7; ++q)
      if (q < cq) a4[q] = rr4[q];
    for (int l = 0; l < 64; ++l) {
      float ev = (float)sEi[k * 64 + (l ^ (k & 31))];
      const float4* xr = (const float4*)&Xs[l * 100 + c0];   // broadcast b128
#pragma unroll
      for (int q = 0; q < 7; ++q) {
        if (q < cq) {
          float4 x4 = xr[q];
          a4[q].x -= ev * x4.x; a4[q].y -= ev * x4.y;
          a4[q].z -= ev * x4.z; a4[q].w -= ev * x4.w;
        }
      }
    }
#pragma unroll
    for (int q = 0; q < 7; ++q) {
      if (q < cq) {
        float4 o = make_float4(alpha * a4[q].x, alpha * a4[q].y,
                               alpha * a4[q].z, alpha * a4[q].w);
        *(float4*)&Xd[k * 100 + c0 + 4 * q] = o;
      }
    }
    __syncthreads();
    float* t = Xs; Xs = Xd; Xd = t;
  }
  // final X in sXa (6 swaps). Stores:
  for (int e = tid; e < 6400; e += 256) Wr[e] = sXa[e];   // identity layout
  for (int e = tid; e < 6400; e += 256) {
    int c = e >> 6, kk = e & 63;
    Wc[e] = sXa[kk * 100 + c];
  }
  // G = X X^T: lane k holds row k in regs; broadcast row i.
  float4 xl[25];
#pragma unroll
  for (int q = 0; q < 25; ++q) xl[q] = *(const float4*)&sXa[k * 100 + 4 * q];
  for (int ii = 0; ii < 16; ++ii) {
    int i = wv * 16 + ii;
    const float4* xi = (const float4*)&sXa[i * 100];
    float d0 = 0.f, d1 = 0.f, d2 = 0.f, d3 = 0.f;
#pragma unroll
    for (int q = 0; q < 25; ++q) {
      float4 b = xi[q];
      d0 += xl[q].x * b.x; d1 += xl[q].y * b.y;
      d2 += xl[q].z * b.z; d3 += xl[q].w * b.w;
    }
    G[i * 64 + k] = (d0 + d1) + (d2 + d3);
  }
}

// K3: per-column P = W@Ybuf_col (sparse over set classes) + 55*U_col, then
// exact sequential GS sign sweep reading G from GLOBAL with wave-uniform
// addresses (s_load path; no LDS for G).
__global__ __launch_bounds__(256) void k3_gs(
    const float* __restrict__ U, const float* __restrict__ u,
    const int* __restrict__ owner, const float* __restrict__ Wc,
    const float* __restrict__ Gm, u64* __restrict__ Bmask,
    u64* __restrict__ Brow, const u64* __restrict__ Ymask) {
  __shared__ float sW[100 * 68];   // [c][i], stride 68 (bank-spread for lane-varying c)
  for (int t = threadIdx.x; t < 6400; t += 256) {
    int c = t >> 6, i = t & 63;
    sW[c * 68 + i] = Wc[t];
  }
  __syncthreads();
  int g = blockIdx.x * 4 + (threadIdx.x >> 6);
  int lane = threadIdx.x & 63;
  if (g >= NGRP) return;
  int j = g * 64 + lane;
  bool act = j < NT;
  int jc = act ? j : NT - 1;
  int ow = owner[jc];
  float p[64];
  if (ow >= 0) {
#pragma unroll
    for (int i = 0; i < 64; ++i) p[i] = ETA_MU * u[ow * 64 + i];
  } else {
#pragma unroll
    for (int i = 0; i < 64; ++i) p[i] = ETA_MU * U[(size_t)i * NT + jc];
  }
  u64 y0 = Ymask[2 * jc], y1 = Ymask[2 * jc + 1];
  // sparse accumulation: identical fp32 result (skipped terms add exactly 0),
  // same ascending-c order as dense
  u64 mm = y0;
  while (mm) {
    int c = __builtin_ctzll(mm); mm &= mm - 1;
    const float4* wr = (const float4*)&sW[c * 68];
#pragma unroll
    for (int q = 0; q < 16; ++q) {
      float4 wvv = wr[q];
      p[4 * q + 0] += wvv.x; p[4 * q + 1] += wvv.y;
      p[4 * q + 2] += wvv.z; p[4 * q + 3] += wvv.w;
    }
  }
  mm = y1;
  while (mm) {
    int c = 64 + __builtin_ctzll(mm); mm &= mm - 1;
    const float4* wr = (const float4*)&sW[c * 68];
#pragma unroll
    for (int q = 0; q < 16; ++q) {
      float4 wvv = wr[q];
      p[4 * q + 0] += wvv.x; p[4 * q + 1] += wvv.y;
      p[4 * q + 2] += wvv.z; p[4 * q + 3] += wvv.w;
    }
  }
  u64 bm = Bmask[jc];
  float bf[64];
#pragma unroll
  for (int k = 0; k < 64; ++k) bf[k] = ((bm >> k) & 1ull) ? 1.0f : -1.0f;
#pragma unroll
  for (int i = 0; i < 64; ++i) {
    const float* gr = &Gm[i * 64];   // wave-uniform address -> scalar loads
    float d0 = 0.f, d1 = 0.f, d2 = 0.f, d3 = 0.f;
#pragma unroll
    for (int q = 0; q < 16; ++q) {
      d0 += gr[4 * q + 0] * bf[4 * q + 0];
      d1 += gr[4 * q + 1] * bf[4 * q + 1];
      d2 += gr[4 * q + 2] * bf[4 * q + 2];
      d3 += gr[4 * q + 3] * bf[4 * q + 3];
    }
    float val = p[i] - ((d0 + d1) + (d2 + d3)) + gr[i] * bf[i];
    bf[i] = (val > 0.0f) ? 1.0f : -1.0f;
  }
  u64 nm = 0;
#pragma unroll
  for (int k = 0; k < 64; ++k)
    if (bf[k] > 0.0f) nm |= 1ull << k;
  if (!act) nm = 0;
  if (act) Bmask[j] = nm;
  u64 tb = transpose64(nm, lane);
  Brow[(size_t)lane * WPR + g] = tb;
}

// L1: likelihood sum over 128 x 100000; u/ybatch read with wave-uniform
// addresses (scalar path), per-column U in VGPRs.
__global__ __launch_bounds__(256) void l1_like(
    const float* __restrict__ U, const float* __restrict__ u,
    const int* __restrict__ owner, const u64* __restrict__ Ymask,
    const u64* __restrict__ ybatch, double* __restrict__ acc) {
  int g = blockIdx.x * 4 + (threadIdx.x >> 6);
  int lane = threadIdx.x & 63;
  double lsum = 0.0;
  if (g < NGRP) {
    int j = g * 64 + lane;
    if (j < NT) {
      float uc[64];
      int ow = owner[j];
      if (ow >= 0) {
#pragma unroll
        for (int i = 0; i < 64; ++i) uc[i] = u[ow * 64 + i];
      } else {
#pragma unroll
        for (int i = 0; i < 64; ++i) uc[i] = U[(size_t)i * NT + j];
      }
      u64 y0 = Ymask[2 * j], y1 = Ymask[2 * j + 1];
      for (int b = 0; b < 128; ++b) {
        const float* ub = &u[b * 64];   // wave-uniform -> scalar loads
        float d0 = 0.f, d1 = 0.f, d2 = 0.f, d3 = 0.f;
#pragma unroll
        for (int q = 0; q < 16; ++q) {
          d0 += ub[4 * q + 0] * uc[4 * q + 0];
          d1 += ub[4 * q + 1] * uc[4 * q + 1];
          d2 += ub[4 * q + 2] * uc[4 * q + 2];
          d3 += ub[4 * q + 3] * uc[4 * q + 3];
        }
        float ip = 0.5f * ((d0 + d1) + (d2 + d3));
        bool s = ((ybatch[2 * b] & y0) | (ybatch[2 * b + 1] & y1)) != 0ull;
        float a = fabsf(ip);
        float like = __logf(1.0f + __expf(-a)) + fmaxf(ip, 0.0f) - (s ? ip : 0.0f);
        lsum += (double)like;
      }
    }
  }
  lsum = wave_reduce_f64(lsum);
  if (lane == 0) atomicAdd(&acc[0], lsum);
}

// L2 + finalize: cl_loss + reg_loss, then combine with acc[0] (l1 done).
__global__ __launch_bounds__(256) void l2_fin(
    const float* __restrict__ Wr, const float* __restrict__ y,
    const int* __restrict__ ind, const u64* __restrict__ Bmask,
    const double* __restrict__ acc, float* __restrict__ out) {
  __shared__ float sw[6400];   // W[i*100+c]
  __shared__ u64 sbm[128];
  __shared__ double dred[8];
  int tid = threadIdx.x;
  for (int t = tid; t < 6400; t += 256) sw[t] = Wr[t];
  if (tid < 128) sbm[tid] = Bmask[ind[tid]];
  __syncthreads();
  double cls = 0.0, regs = 0.0;
  for (int e = tid; e < 12800; e += 256) {
    int c = e >> 7, b = e & 127;
    u64 bm = sbm[b];
    float s = 0.0f;
#pragma unroll
    for (int i = 0; i < 64; ++i) {
      float w = sw[i * 100 + c];
      s += ((bm >> i) & 1ull) ? w : -w;
    }
    float d = y[b * 100 + c] - s;
    cls += (double)(d * d);
  }
  for (int e = tid; e < 6400; e += 256) {
    float w = sw[e];
    regs += (double)(w * w);
  }
  cls = wave_reduce_f64(cls);
  regs = wave_reduce_f64(regs);
  int wv = tid >> 6;
  if ((tid & 63) == 0) { dred[wv] = cls; dred[4 + wv] = regs; }
  __syncthreads();
  if (tid == 0) {
    double c = dred[0] + dred[1] + dred[2] + dred[3];
    double r = dred[4] + dred[5] + dred[6] + dred[7];
    out[0] = (float)(acc[0] * (1.0 / 12800000.0) + c * (1.0 / 12800.0) +
                     r * (0.1 / 6400.0));
  }
}

extern "C" void kernel_launch(void* const* d_in, const int* in_sizes, int n_in,
                              void* d_out, int out_size, void* d_ws, size_t ws_size,
                              hipStream_t stream) {
  const float* u    = (const float*)d_in[0];
  const float* y    = (const float*)d_in[1];
  const int*   ind  = (const int*)d_in[2];
  const float* U    = (const float*)d_in[3];
  const float* B    = (const float*)d_in[4];
  const float* Ybuf = (const float*)d_in[5];
  char* ws = (char*)d_ws;
  double* acc   = (double*)(ws + 0);
  u64* Bmask    = (u64*)(ws + 256);
  u64* Ymask    = (u64*)(ws + 800256);
  u64* Brow     = (u64*)(ws + 2400256);
  u64* Yrow     = (u64*)(ws + 3203072);
  u64* ybatch   = (u64*)(ws + 4457472);
  int* popcY    = (int*)(ws + 4459520);
  int* S_part   = (int*)(ws + 4460032);
  int* R_part   = (int*)(ws + 4525568);
  float* Wr     = (float*)(ws + 4627968);
  float* Wc     = (float*)(ws + 4653568);
  float* G      = (float*)(ws + 4679168);
  int* owner    = (int*)(ws + 4695552);

  init_acc<<<1, 64, 0, stream>>>(acc);
  build_colmasks<<<(NT + 255) / 256, 256, 0, stream>>>(B, Ybuf, Bmask, Ymask, owner);
  scatter_y<<<1, 128, 0, stream>>>(y, ind, Ymask, ybatch, owner);
  build_rows<<<391, 256, 0, stream>>>(Bmask, Ymask, Brow, Yrow);
  popcY_k<<<100, 256, 0, stream>>>(Yrow, popcY);
  for (int it = 0; it < 10; ++it) {
    k1_sr<<<dim3(64, 4), 256, 0, stream>>>(Brow, Yrow, S_part, R_part);
    k2_solve<<<1, 256, 0, stream>>>(S_part, R_part, popcY, Wr, Wc, G);
    k3_gs<<<391, 256, 0, stream>>>(U, u, owner, Wc, G, Bmask, Brow, Ymask);
  }
  l1_like<<<391, 256, 0, stream>>>(U, u, owner, Ymask, ybatch, acc);
  l2_fin<<<1, 256, 0, stream>>>(Wr, y, ind, Bmask, acc, (float*)d_out);
}